// Round 9
// baseline (82.921 us; speedup 1.0000x reference)
//
#include <hip/hip_runtime.h>
#include <hip/hip_fp16.h>

// DeepseekV4HashRouter: B=4,S=4096,D=2048,E=256,K=8,V=128000
#define DIM    2048
#define NEXP   256
#define TOPK   8
#define RSCALE 2.5f
#define BM     64
#define BK     64
#define NT     (DIM / BK)   // 32 K-steps
#define NTHR   256          // 4 waves, wave w -> expert strip w*64

// LDS layout (bytes): A bufs 3 x 16384 (f32 [64][64], 16B-slot swizzled)
//                     B bufs 3 x 32768 (f16 [256][64], 16B-slot swizzled)
#define A_OFF  0
#define A_SZ   16384
#define B_OFF  49152
#define B_SZ   32768
#define SMEM_SZ 147456

typedef _Float16 h8 __attribute__((ext_vector_type(8)));
typedef float f32x4 __attribute__((ext_vector_type(4)));

__device__ __forceinline__ unsigned int pkh(float x, float y) {
    return __builtin_bit_cast(unsigned int, __builtin_amdgcn_cvt_pkrtz(x, y));
}

__global__ __launch_bounds__(256) void convert_weight_f16(
    const float* __restrict__ w, unsigned int* __restrict__ wh, int n4) {
    int i = blockIdx.x * blockDim.x + threadIdx.x;  // over float4s
    if (i < n4) {
        float4 f = reinterpret_cast<const float4*>(w)[i];
        uint2 o;
        o.x = pkh(f.x, f.y);
        o.y = pkh(f.z, f.w);
        reinterpret_cast<uint2*>(wh)[i] = o;
    }
}

// Dense MFMA router: block = 64 tokens x 256 experts, K = 2048.
// Grid = M/64 = 256 blocks (1/CU). 3-buffer depth-2 DMA pipeline,
// counted vmcnt (T3/T4), zero ds_writes, one s_barrier per K-step.
__global__ __launch_bounds__(NTHR) void router_mfma3(
    const float* __restrict__ hidden,   // [M, D] fp32
    const int* __restrict__ token_ids,  // [M] int32
    const ushort* __restrict__ wh,      // [E, D] f16
    const int* __restrict__ tid2eid,    // [V, K] int32
    float* __restrict__ out,            // probs [M,E] then map [M,E]
    int M) {
    __shared__ alignas(16) char smem[SMEM_SZ];

    const int t  = threadIdx.x;
    const int w  = t >> 6;
    const int l  = t & 63;
    const int n0 = blockIdx.x * BM;

    // Stage K-tile kt into buffer bi: 12 global_load_lds per wave
    // (A: 4 issues of 1KB = 4 f32 rows each; B: 8 issues of 1KB = 8 f16 rows).
    // XOR-involution swizzle applied on the GLOBAL source (rule #21).
    auto stage = [&](int kt, int bi) {
        {
            const int lr = l >> 4;      // row within 4-row group
            const int s  = l & 15;      // 16B slot within 256B row
#pragma unroll
            for (int i = 0; i < 4; ++i) {
                const int j = w * 4 + i;          // 0..15
                const int r = j * 4 + lr;         // token row 0..63
                const int gs = s ^ (r & 15);
                const float* g = hidden + (size_t)(n0 + r) * DIM + kt * BK + gs * 4;
                const char* lp = smem + A_OFF + bi * A_SZ + j * 1024;
                __builtin_amdgcn_global_load_lds(
                    (const unsigned int __attribute__((address_space(1)))*)g,
                    (unsigned int __attribute__((address_space(3)))*)lp, 16, 0, 0);
            }
        }
        {
            const int lr = l >> 3;      // expert row within 8-row group
            const int s  = l & 7;       // 16B slot within 128B row
#pragma unroll
            for (int i = 0; i < 8; ++i) {
                const int j = w * 8 + i;          // 0..31
                const int e = j * 8 + lr;         // expert row 0..255
                const int gs = s ^ (e & 7);
                const ushort* g = wh + (size_t)e * DIM + kt * BK + gs * 8;
                const char* lp = smem + B_OFF + bi * B_SZ + j * 1024;
                __builtin_amdgcn_global_load_lds(
                    (const unsigned int __attribute__((address_space(1)))*)g,
                    (unsigned int __attribute__((address_space(3)))*)lp, 16, 0, 0);
            }
        }
    };

    // Prologue: fill buffers 0,1; wait for buffer 0 (leave 1 in flight).
    stage(0, 0);
    stage(1, 1);
    asm volatile("s_waitcnt vmcnt(12)" ::: "memory");
    __builtin_amdgcn_s_barrier();

    f32x4 acc[4][4] = {};
    const int row16 = l & 15;
    const int quad  = l >> 4;

    for (int kt = 0; kt < NT; ++kt) {
        const int bi = kt % 3;
        if (kt + 2 < NT) stage(kt + 2, (kt + 2) % 3);

        const float*  aB = reinterpret_cast<const float*>(smem + A_OFF + bi * A_SZ);
        const ushort* bB = reinterpret_cast<const ushort*>(smem + B_OFF + bi * B_SZ);
#pragma unroll
        for (int kk = 0; kk < 2; ++kk) {
            const int bb = kk * 4 + quad;         // k-8-slice index 0..7
            h8 af[4], bf[4];
#pragma unroll
            for (int mi = 0; mi < 4; ++mi) {
                const int r  = mi * 16 + row16;
                const int s0 = (bb * 2) ^ (r & 15);
                const int s1 = (bb * 2 + 1) ^ (r & 15);
                const float4 a0 = *reinterpret_cast<const float4*>(aB + r * 64 + s0 * 4);
                const float4 a1 = *reinterpret_cast<const float4*>(aB + r * 64 + s1 * 4);
                uint4 u;
                u.x = pkh(a0.x, a0.y); u.y = pkh(a0.z, a0.w);
                u.z = pkh(a1.x, a1.y); u.w = pkh(a1.z, a1.w);
                af[mi] = __builtin_bit_cast(h8, u);
            }
#pragma unroll
            for (int ni = 0; ni < 4; ++ni) {
                const int c = w * 64 + ni * 16 + row16;
                bf[ni] = *reinterpret_cast<const h8*>(bB + c * 64 + ((bb ^ (c & 7)) * 8));
            }
#pragma unroll
            for (int mi = 0; mi < 4; ++mi)
#pragma unroll
                for (int ni = 0; ni < 4; ++ni)
                    acc[mi][ni] = __builtin_amdgcn_mfma_f32_16x16x32_f16(
                        af[mi], bf[ni], acc[mi][ni], 0, 0, 0);
        }

        if (kt + 2 < NT) {
            // next buffer's stages (issued at kt+1... wait: at kt-1) done;
            // leave this iteration's 12 issues in flight across the barrier.
            asm volatile("s_waitcnt vmcnt(12)" ::: "memory");
            __builtin_amdgcn_s_barrier();
        } else if (kt + 1 < NT) {
            asm volatile("s_waitcnt vmcnt(0)" ::: "memory");
            __builtin_amdgcn_s_barrier();
        }
    }
    __syncthreads();   // full drain before C overlay reuses the staging LDS

    // Scatter logits into C-LDS overlay. D map: col=lane&15, row=(lane>>4)*4+r.
    float (*cLds)[NEXP + 1] = reinterpret_cast<float (*)[NEXP + 1]>(smem);
#pragma unroll
    for (int mi = 0; mi < 4; ++mi) {
#pragma unroll
        for (int ni = 0; ni < 4; ++ni) {
            const int m = mi * 16 + quad * 4;
            const int c = w * 64 + ni * 16 + row16;
#pragma unroll
            for (int r = 0; r < 4; ++r)
                cLds[m + r][c] = acc[mi][ni][r];
        }
    }
    __syncthreads();

    // Epilogue: wave w handles tokens w*16 .. w*16+15.
    for (int tt = 0; tt < 16; ++tt) {
        const int tok = w * 16 + tt;
        const int n   = n0 + tok;
        const int tid = token_ids[n];
        float sval = 0.0f;
        int eown = -1;
        if (l < TOPK) {
            eown = tid2eid[(size_t)tid * TOPK + l];
            const float logit = cLds[tok][eown];
            const float sp = fmaxf(logit, 0.0f) + log1pf(expf(-fabsf(logit)));
            sval = sqrtf(sp);
        }
        float sc[TOPK]; int eidx[TOPK];
        float denom = 0.0f;
#pragma unroll
        for (int k = 0; k < TOPK; ++k) {
            sc[k]   = __shfl(sval, k, 64);
            eidx[k] = __shfl(eown, k, 64);
            denom  += sc[k];
        }
        const float inv = RSCALE / fmaxf(denom, 1e-12f);
        float4 p, mv;
        float* pp = reinterpret_cast<float*>(&p);
        float* mm = reinterpret_cast<float*>(&mv);
#pragma unroll
        for (int c = 0; c < 4; ++c) {
            const int e = l * 4 + c;
            float pv = 0.0f, fv = 0.0f;
#pragma unroll
            for (int k = 0; k < TOPK; ++k)
                if (eidx[k] == e) { pv = sc[k] * inv; fv = 1.0f; }
            pp[c] = pv; mm[c] = fv;
        }
        reinterpret_cast<float4*>(out + (size_t)n * NEXP)[l] = p;
        reinterpret_cast<float4*>(out + (size_t)(M + n) * NEXP)[l] = mv;
    }
}

// Fallback (no workspace / M not multiple of 64): fp32 gather, wave per token.
__global__ __launch_bounds__(256) void router_fp32(
    const float* __restrict__ hidden, const int* __restrict__ token_ids,
    const float* __restrict__ weight, const int* __restrict__ tid2eid,
    float* __restrict__ out, int N) {
    const int lane = threadIdx.x & 63;
    const int n = blockIdx.x * 4 + (threadIdx.x >> 6);
    if (n >= N) return;
    const int tid = token_ids[n];
    const int* er = tid2eid + (size_t)tid * TOPK;
    int eidx[TOPK];
#pragma unroll
    for (int k = 0; k < TOPK; ++k) eidx[k] = er[k];
    const float4* h4 = reinterpret_cast<const float4*>(hidden + (size_t)n * DIM);
    float acc[TOPK] = {};
#pragma unroll
    for (int j = 0; j < 4; ++j) {
        const float4 a = h4[j * 128 + lane * 2];
        const float4 b = h4[j * 128 + lane * 2 + 1];
#pragma unroll
        for (int k = 0; k < TOPK; ++k) {
            const float4* wr = reinterpret_cast<const float4*>(weight + (size_t)eidx[k] * DIM);
            const float4 wa = wr[j * 128 + lane * 2];
            const float4 wb = wr[j * 128 + lane * 2 + 1];
            acc[k] += a.x * wa.x + a.y * wa.y + a.z * wa.z + a.w * wa.w
                    + b.x * wb.x + b.y * wb.y + b.z * wb.z + b.w * wb.w;
        }
    }
#pragma unroll
    for (int k = 0; k < TOPK; ++k) {
        float v = acc[k];
#pragma unroll
        for (int m = 1; m < 64; m <<= 1) v += __shfl_xor(v, m, 64);
        acc[k] = v;
    }
    float sval = 0.0f;
    if (lane < TOPK) {
        const float sp = fmaxf(acc[lane], 0.0f) + log1pf(expf(-fabsf(acc[lane])));
        sval = sqrtf(sp);
    }
    float sc[TOPK]; float denom = 0.0f;
#pragma unroll
    for (int k = 0; k < TOPK; ++k) { sc[k] = __shfl(sval, k, 64); denom += sc[k]; }
    const float inv = RSCALE / fmaxf(denom, 1e-12f);
    float4 p, mv;
    float* pp = reinterpret_cast<float*>(&p);
    float* mm = reinterpret_cast<float*>(&mv);
#pragma unroll
    for (int c = 0; c < 4; ++c) {
        const int e = lane * 4 + c;
        float pv = 0.0f, fv = 0.0f;
#pragma unroll
        for (int k = 0; k < TOPK; ++k)
            if (eidx[k] == e) { pv = sc[k] * inv; fv = 1.0f; }
        pp[c] = pv; mm[c] = fv;
    }
    reinterpret_cast<float4*>(out + (size_t)n * NEXP)[lane] = p;
    reinterpret_cast<float4*>(out + (size_t)(N + n) * NEXP)[lane] = mv;
}

extern "C" void kernel_launch(void* const* d_in, const int* in_sizes, int n_in,
                              void* d_out, int out_size, void* d_ws, size_t ws_size,
                              hipStream_t stream) {
    const float* hidden    = (const float*)d_in[0];
    const int*   token_ids = (const int*)d_in[1];   // int64 in ref -> int32 here
    const float* weight    = (const float*)d_in[2];
    const int*   tid2eid   = (const int*)d_in[3];
    float* out = (float*)d_out;
    const int M = in_sizes[1];  // B*S tokens

    const size_t need = (size_t)NEXP * DIM * sizeof(ushort);  // 1 MiB
    if (ws_size >= need && (M % BM) == 0) {
        unsigned int* wh = (unsigned int*)d_ws;
        const int n4 = NEXP * DIM / 4;
        convert_weight_f16<<<(n4 + 255) / 256, 256, 0, stream>>>(weight, wh, n4);
        router_mfma3<<<M / BM, NTHR, 0, stream>>>(hidden, token_ids,
                                                  (const ushort*)wh, tid2eid, out, M);
    } else {
        router_fp32<<<(M + 3) / 4, 256, 0, stream>>>(hidden, token_ids, weight,
                                                     tid2eid, out, M);
    }
}

// Round 10
// 63.273 us; speedup vs baseline: 1.3105x; 1.3105x over previous
//
#include <hip/hip_runtime.h>
#include <hip/hip_fp16.h>

// DeepseekV4HashRouter: B=4,S=4096,D=2048,E=256,K=8,V=128000
#define DIM    2048
#define NEXP   256
#define TOPK   8
#define RSCALE 2.5f
#define BM     64
#define BK     64
#define NT     (DIM / BK)   // 32 K-steps
#define NTHR   512          // 8 waves: 2 (token) x 4 (expert) tiles

// LDS: A bufs 3 x 16KB (f32 [64][64], 16B-slot XOR-swizzled)
//      B bufs 3 x 32KB (f16 [256][64], 16B-slot XOR-swizzled)
#define A_OFF  0
#define A_SZ   16384
#define B_OFF  49152
#define B_SZ   32768
#define SMEM_SZ 147456

typedef _Float16 h8 __attribute__((ext_vector_type(8)));
typedef float f32x4 __attribute__((ext_vector_type(4)));

__device__ __forceinline__ unsigned int pkh(float x, float y) {
    return __builtin_bit_cast(unsigned int, __builtin_amdgcn_cvt_pkrtz(x, y));
}

__global__ __launch_bounds__(256) void convert_weight_f16(
    const float* __restrict__ w, unsigned int* __restrict__ wh, int n4) {
    int i = blockIdx.x * blockDim.x + threadIdx.x;  // over float4s
    if (i < n4) {
        float4 f = reinterpret_cast<const float4*>(w)[i];
        uint2 o;
        o.x = pkh(f.x, f.y);
        o.y = pkh(f.z, f.w);
        reinterpret_cast<uint2*>(wh)[i] = o;
    }
}

// Dense MFMA router: block = 64 tokens x 256 experts, K = 2048.
// Grid = 256 blocks (1/CU), 8 waves (2/SIMD). 3-buffer depth-2 DMA
// pipeline, counted vmcnt (never 0 in steady state), zero ds_writes.
__global__ __launch_bounds__(NTHR) void router_mfma4(
    const float* __restrict__ hidden,   // [M, D] fp32
    const int* __restrict__ token_ids,  // [M] int32
    const ushort* __restrict__ wh,      // [E, D] f16
    const int* __restrict__ tid2eid,    // [V, K] int32
    float* __restrict__ out,            // probs [M,E] then map [M,E]
    int M) {
    __shared__ alignas(16) char smem[SMEM_SZ];

    const int t  = threadIdx.x;
    const int w  = t >> 6;        // wave 0..7
    const int l  = t & 63;
    const int wm = w >> 2;        // token half: rows wm*32 ..
    const int wn = w & 3;         // expert strip: cols wn*64 ..
    const int n0 = blockIdx.x * BM;

    // Stage K-tile kt into buffer bi: 6 global_load_lds per wave.
    // XOR-involution swizzle applied on the GLOBAL source (rule #21).
    auto stage = [&](int kt, int bi) {
        {   // A: 16 chunks of 1KB (4 f32 rows each); wave w -> chunks 2w, 2w+1
            const int lr = l >> 4;
            const int s  = l & 15;
#pragma unroll
            for (int i = 0; i < 2; ++i) {
                const int j  = w * 2 + i;
                const int r  = j * 4 + lr;
                const int gs = s ^ (r & 15);
                const float* g = hidden + (size_t)(n0 + r) * DIM + kt * BK + gs * 4;
                const char* lp = smem + A_OFF + bi * A_SZ + j * 1024;
                __builtin_amdgcn_global_load_lds(
                    (const unsigned int __attribute__((address_space(1)))*)g,
                    (unsigned int __attribute__((address_space(3)))*)lp, 16, 0, 0);
            }
        }
        {   // B: 32 chunks of 1KB (8 f16 rows each); wave w -> chunks 4w..4w+3
            const int lr = l >> 3;
            const int s  = l & 7;
#pragma unroll
            for (int i = 0; i < 4; ++i) {
                const int j  = w * 4 + i;
                const int e  = j * 8 + lr;
                const int gs = s ^ (e & 7);
                const ushort* g = wh + (size_t)e * DIM + kt * BK + gs * 8;
                const char* lp = smem + B_OFF + bi * B_SZ + j * 1024;
                __builtin_amdgcn_global_load_lds(
                    (const unsigned int __attribute__((address_space(1)))*)g,
                    (unsigned int __attribute__((address_space(3)))*)lp, 16, 0, 0);
            }
        }
    };

    // Prologue: fill buffers 0,1; wait for buffer 0 (leave 1's 6 in flight).
    stage(0, 0);
    stage(1, 1);
    asm volatile("s_waitcnt vmcnt(6)" ::: "memory");
    __builtin_amdgcn_s_barrier();

    f32x4 acc[2][4] = {};
    const int row16 = l & 15;
    const int quad  = l >> 4;

    for (int kt = 0; kt < NT; ++kt) {
        const int bi = kt % 3;
        if (kt + 2 < NT) stage(kt + 2, (kt + 2) % 3);

        const float*  aB = reinterpret_cast<const float*>(smem + A_OFF + bi * A_SZ);
        const ushort* bB = reinterpret_cast<const ushort*>(smem + B_OFF + bi * B_SZ);
#pragma unroll
        for (int kk = 0; kk < 2; ++kk) {
            const int bb = kk * 4 + quad;         // k-8-slice index 0..7
            h8 af[2], bf[4];
#pragma unroll
            for (int mi = 0; mi < 2; ++mi) {
                const int r  = wm * 32 + mi * 16 + row16;
                const int s0 = (bb * 2) ^ (r & 15);
                const int s1 = (bb * 2 + 1) ^ (r & 15);
                const float4 a0 = *reinterpret_cast<const float4*>(aB + r * 64 + s0 * 4);
                const float4 a1 = *reinterpret_cast<const float4*>(aB + r * 64 + s1 * 4);
                uint4 u;
                u.x = pkh(a0.x, a0.y); u.y = pkh(a0.z, a0.w);
                u.z = pkh(a1.x, a1.y); u.w = pkh(a1.z, a1.w);
                af[mi] = __builtin_bit_cast(h8, u);
            }
#pragma unroll
            for (int ni = 0; ni < 4; ++ni) {
                const int c = wn * 64 + ni * 16 + row16;
                bf[ni] = *reinterpret_cast<const h8*>(bB + c * 64 + ((bb ^ (c & 7)) * 8));
            }
#pragma unroll
            for (int mi = 0; mi < 2; ++mi)
#pragma unroll
                for (int ni = 0; ni < 4; ++ni)
                    acc[mi][ni] = __builtin_amdgcn_mfma_f32_16x16x32_f16(
                        af[mi], bf[ni], acc[mi][ni], 0, 0, 0);
        }

        if (kt + 2 < NT) {
            asm volatile("s_waitcnt vmcnt(6)" ::: "memory");  // drain kt+1's batch
            __builtin_amdgcn_s_barrier();
        } else if (kt + 1 < NT) {
            asm volatile("s_waitcnt vmcnt(0)" ::: "memory");  // drain last stage
            __builtin_amdgcn_s_barrier();
        }
    }
    __syncthreads();   // full drain before C overlay reuses the staging LDS

    // Scatter logits into C-LDS overlay. D map: col=lane&15, row=quad*4+r.
    float (*cLds)[NEXP + 1] = reinterpret_cast<float (*)[NEXP + 1]>(smem);
#pragma unroll
    for (int mi = 0; mi < 2; ++mi) {
#pragma unroll
        for (int ni = 0; ni < 4; ++ni) {
            const int m = wm * 32 + mi * 16 + quad * 4;
            const int c = wn * 64 + ni * 16 + row16;
#pragma unroll
            for (int r = 0; r < 4; ++r)
                cLds[m + r][c] = acc[mi][ni][r];
        }
    }
    __syncthreads();

    // Epilogue: wave w handles tokens w*8 .. w*8+7.
#pragma unroll
    for (int tt = 0; tt < 8; ++tt) {
        const int tok = w * 8 + tt;
        const int n   = n0 + tok;
        const int tid = token_ids[n];
        float sval = 0.0f;
        int eown = -1;
        if (l < TOPK) {
            eown = tid2eid[(size_t)tid * TOPK + l];
            const float logit = cLds[tok][eown];
            const float sp = fmaxf(logit, 0.0f) + log1pf(expf(-fabsf(logit)));
            sval = sqrtf(sp);
        }
        float sc[TOPK]; int eidx[TOPK];
        float denom = 0.0f;
#pragma unroll
        for (int k = 0; k < TOPK; ++k) {
            sc[k]   = __shfl(sval, k, 64);
            eidx[k] = __shfl(eown, k, 64);
            denom  += sc[k];
        }
        const float inv = RSCALE / fmaxf(denom, 1e-12f);
        float4 p, mv;
        float* pp = reinterpret_cast<float*>(&p);
        float* mm = reinterpret_cast<float*>(&mv);
#pragma unroll
        for (int c = 0; c < 4; ++c) {
            const int e = l * 4 + c;
            float pv = 0.0f, fv = 0.0f;
#pragma unroll
            for (int k = 0; k < TOPK; ++k)
                if (eidx[k] == e) { pv = sc[k] * inv; fv = 1.0f; }
            pp[c] = pv; mm[c] = fv;
        }
        reinterpret_cast<float4*>(out + (size_t)n * NEXP)[l] = p;
        reinterpret_cast<float4*>(out + (size_t)(M + n) * NEXP)[l] = mv;
    }
}

// Fallback (no workspace / M not multiple of 64): fp32 gather, wave per token.
__global__ __launch_bounds__(256) void router_fp32(
    const float* __restrict__ hidden, const int* __restrict__ token_ids,
    const float* __restrict__ weight, const int* __restrict__ tid2eid,
    float* __restrict__ out, int N) {
    const int lane = threadIdx.x & 63;
    const int n = blockIdx.x * 4 + (threadIdx.x >> 6);
    if (n >= N) return;
    const int tid = token_ids[n];
    const int* er = tid2eid + (size_t)tid * TOPK;
    int eidx[TOPK];
#pragma unroll
    for (int k = 0; k < TOPK; ++k) eidx[k] = er[k];
    const float4* h4 = reinterpret_cast<const float4*>(hidden + (size_t)n * DIM);
    float acc[TOPK] = {};
#pragma unroll
    for (int j = 0; j < 4; ++j) {
        const float4 a = h4[j * 128 + lane * 2];
        const float4 b = h4[j * 128 + lane * 2 + 1];
#pragma unroll
        for (int k = 0; k < TOPK; ++k) {
            const float4* wr = reinterpret_cast<const float4*>(weight + (size_t)eidx[k] * DIM);
            const float4 wa = wr[j * 128 + lane * 2];
            const float4 wb = wr[j * 128 + lane * 2 + 1];
            acc[k] += a.x * wa.x + a.y * wa.y + a.z * wa.z + a.w * wa.w
                    + b.x * wb.x + b.y * wb.y + b.z * wb.z + b.w * wb.w;
        }
    }
#pragma unroll
    for (int k = 0; k < TOPK; ++k) {
        float v = acc[k];
#pragma unroll
        for (int m = 1; m < 64; m <<= 1) v += __shfl_xor(v, m, 64);
        acc[k] = v;
    }
    float sval = 0.0f;
    if (lane < TOPK) {
        const float sp = fmaxf(acc[lane], 0.0f) + log1pf(expf(-fabsf(acc[lane])));
        sval = sqrtf(sp);
    }
    float sc[TOPK]; float denom = 0.0f;
#pragma unroll
    for (int k = 0; k < TOPK; ++k) { sc[k] = __shfl(sval, k, 64); denom += sc[k]; }
    const float inv = RSCALE / fmaxf(denom, 1e-12f);
    float4 p, mv;
    float* pp = reinterpret_cast<float*>(&p);
    float* mm = reinterpret_cast<float*>(&mv);
#pragma unroll
    for (int c = 0; c < 4; ++c) {
        const int e = lane * 4 + c;
        float pv = 0.0f, fv = 0.0f;
#pragma unroll
        for (int k = 0; k < TOPK; ++k)
            if (eidx[k] == e) { pv = sc[k] * inv; fv = 1.0f; }
        pp[c] = pv; mm[c] = fv;
    }
    reinterpret_cast<float4*>(out + (size_t)n * NEXP)[lane] = p;
    reinterpret_cast<float4*>(out + (size_t)(N + n) * NEXP)[lane] = mv;
}

extern "C" void kernel_launch(void* const* d_in, const int* in_sizes, int n_in,
                              void* d_out, int out_size, void* d_ws, size_t ws_size,
                              hipStream_t stream) {
    const float* hidden    = (const float*)d_in[0];
    const int*   token_ids = (const int*)d_in[1];   // int64 in ref -> int32 here
    const float* weight    = (const float*)d_in[2];
    const int*   tid2eid   = (const int*)d_in[3];
    float* out = (float*)d_out;
    const int M = in_sizes[1];  // B*S tokens

    const size_t need = (size_t)NEXP * DIM * sizeof(ushort);  // 1 MiB
    if (ws_size >= need && (M % BM) == 0) {
        unsigned int* wh = (unsigned int*)d_ws;
        const int n4 = NEXP * DIM / 4;
        convert_weight_f16<<<(n4 + 255) / 256, 256, 0, stream>>>(weight, wh, n4);
        router_mfma4<<<M / BM, NTHR, 0, stream>>>(hidden, token_ids,
                                                  (const ushort*)wh, tid2eid, out, M);
    } else {
        router_fp32<<<(M + 3) / 4, 256, 0, stream>>>(hidden, token_ids, weight,
                                                     tid2eid, out, M);
    }
}

// Round 11
// 45.975 us; speedup vs baseline: 1.8036x; 1.3762x over previous
//
#include <hip/hip_runtime.h>
#include <hip/hip_fp16.h>

// DeepseekV4HashRouter: B=4,S=4096,D=2048,E=256,K=8,V=128000
#define DIM    2048
#define NEXP   256
#define TOPK   8
#define RSCALE 2.5f
#define WPT    8  // waves (tokens) per 512-thread block

typedef _Float16 h2 __attribute__((ext_vector_type(2)));

__device__ __forceinline__ float dot2(h2 a, h2 b, float c) {
#if __has_builtin(__builtin_amdgcn_fdot2)
    return __builtin_amdgcn_fdot2(a, b, c, false);
#else
    return c + (float)a[0] * (float)b[0] + (float)a[1] * (float)b[1];
#endif
}

__device__ __forceinline__ h2 cvt_pk(float x, float y) {
    return __builtin_bit_cast(h2, __builtin_amdgcn_cvt_pkrtz(x, y));
}

__device__ __forceinline__ h2 as_h2(unsigned int u) {
    return __builtin_bit_cast(h2, u);
}

__global__ __launch_bounds__(256) void convert_weight_f16(
    const float* __restrict__ w, unsigned int* __restrict__ wh, int n4) {
    int i = blockIdx.x * blockDim.x + threadIdx.x;  // over float4s
    if (i < n4) {
        float4 f = reinterpret_cast<const float4*>(w)[i];
        uint2 o;
        o.x = __builtin_bit_cast(unsigned int, cvt_pk(f.x, f.y));
        o.y = __builtin_bit_cast(unsigned int, cvt_pk(f.z, f.w));
        reinterpret_cast<uint2*>(wh)[i] = o;
    }
}

// One 64-lane wave per token; f16 weight + v_dot2; SGPR expert bases;
// j-outer / k-inner for 8 independent loads in flight; VGPR capped for
// 6 waves/SIMD occupancy (24 waves/CU) to hide L2 gather latency.
template <bool F16W>
__global__ __launch_bounds__(512, 6) void router_v5(
    const float* __restrict__ hidden,   // [N, D] fp32
    const int* __restrict__ token_ids,  // [N] int32
    const void* __restrict__ weight,    // [E, D] f16-pairs(u32) or fp32
    const int* __restrict__ tid2eid,    // [V, K] int32
    float* __restrict__ out,            // probs [N,E] then map [N,E]
    int N) {
    const int lane = threadIdx.x & 63;
    const int n = blockIdx.x * WPT + (threadIdx.x >> 6);
    if (n >= N) return;

    // Wave-uniform token id / expert ids -> SGPRs.
    const int tid = __builtin_amdgcn_readfirstlane(token_ids[n]);
    const int* er = tid2eid + (size_t)tid * TOPK;
    int eidx[TOPK];
#pragma unroll
    for (int k = 0; k < TOPK; ++k)
        eidx[k] = __builtin_amdgcn_readfirstlane(er[k]);

    const float4* h4 = reinterpret_cast<const float4*>(hidden + (size_t)n * DIM);

    float acc[TOPK] = {0.f, 0.f, 0.f, 0.f, 0.f, 0.f, 0.f, 0.f};

    if (F16W) {
        // SGPR base pointer per expert row; vaddr = lane*16 shared.
        const uint4* wb[TOPK];
#pragma unroll
        for (int k = 0; k < TOPK; ++k)
            wb[k] = reinterpret_cast<const uint4*>(weight) + (size_t)eidx[k] * (DIM / 8);

#pragma unroll
        for (int j = 0; j < 4; ++j) {
            // 8 independent weight loads (distinct SGPR bases, shared vaddr).
            uint4 wv[TOPK];
#pragma unroll
            for (int k = 0; k < TOPK; ++k) wv[k] = wb[k][j * 64 + lane];
            // this lane's 8 hidden floats for chunk j, packed to 4 f16-pairs
            const float4 a = h4[j * 128 + lane * 2];
            const float4 b = h4[j * 128 + lane * 2 + 1];
            const h2 h0 = cvt_pk(a.x, a.y), h1 = cvt_pk(a.z, a.w);
            const h2 g0 = cvt_pk(b.x, b.y), g1 = cvt_pk(b.z, b.w);
#pragma unroll
            for (int k = 0; k < TOPK; ++k) {
                acc[k] = dot2(h0, as_h2(wv[k].x), acc[k]);
                acc[k] = dot2(h1, as_h2(wv[k].y), acc[k]);
                acc[k] = dot2(g0, as_h2(wv[k].z), acc[k]);
                acc[k] = dot2(g1, as_h2(wv[k].w), acc[k]);
            }
        }
    } else {
        const float* wf = reinterpret_cast<const float*>(weight);
#pragma unroll
        for (int j = 0; j < 4; ++j) {
            const float4 a = h4[j * 128 + lane * 2];
            const float4 b = h4[j * 128 + lane * 2 + 1];
#pragma unroll
            for (int k = 0; k < TOPK; ++k) {
                const float4* wrow = reinterpret_cast<const float4*>(wf + (size_t)eidx[k] * DIM);
                const float4 wa = wrow[j * 128 + lane * 2];
                const float4 wbv = wrow[j * 128 + lane * 2 + 1];
                acc[k] += a.x * wa.x + a.y * wa.y + a.z * wa.z + a.w * wa.w
                        + b.x * wbv.x + b.y * wbv.y + b.z * wbv.z + b.w * wbv.w;
            }
        }
    }

    // Tournament reduce: 8 values/lane -> 1 value/lane in 7 shfls + 3 butterfly.
    const int b0 = lane & 1, b1 = (lane >> 1) & 1, b2 = (lane >> 2) & 1;
    float v4[4];
#pragma unroll
    for (int k = 0; k < 4; ++k) {
        const float send = b0 ? acc[k] : acc[k + 4];
        const float recv = __shfl_xor(send, 1, 64);
        v4[k] = (b0 ? acc[k + 4] : acc[k]) + recv;
    }
    float v2[2];
#pragma unroll
    for (int j = 0; j < 2; ++j) {
        const float send = b1 ? v4[j] : v4[j + 2];
        const float recv = __shfl_xor(send, 2, 64);
        v2[j] = (b1 ? v4[j + 2] : v4[j]) + recv;
    }
    {
        const float send = b2 ? v2[0] : v2[1];
        const float recv = __shfl_xor(send, 4, 64);
        v2[0] = (b2 ? v2[1] : v2[0]) + recv;
    }
    float v = v2[0];
    v += __shfl_xor(v, 8, 64);
    v += __shfl_xor(v, 16, 64);
    v += __shfl_xor(v, 32, 64);
    // Lane l holds logit of expert slot e(l) = 4*b0 + 2*b1 + b2.

    const float sp = fmaxf(v, 0.0f) + log1pf(expf(-fabsf(v)));
    const float score = sqrtf(sp);

    // Slot k lives in lane bit-rev3(k).
    float sc[TOPK];
    float denom = 0.0f;
#pragma unroll
    for (int k = 0; k < TOPK; ++k) {
        const int src = ((k >> 2) & 1) | (k & 2) | ((k & 1) << 2);
        sc[k] = __shfl(score, src, 64);
        denom += sc[k];
    }
    const float inv = RSCALE / fmaxf(denom, 1e-12f);

    // Dense vectorized write: lane l owns experts 4l..4l+3.
    float4 p, m;
    float* pp = reinterpret_cast<float*>(&p);
    float* mm = reinterpret_cast<float*>(&m);
#pragma unroll
    for (int c = 0; c < 4; ++c) {
        const int e = lane * 4 + c;
        float pv = 0.0f, mv = 0.0f;
#pragma unroll
        for (int k = 0; k < TOPK; ++k) {
            if (eidx[k] == e) { pv = sc[k] * inv; mv = 1.0f; }
        }
        pp[c] = pv; mm[c] = mv;
    }
    reinterpret_cast<float4*>(out + (size_t)n * NEXP)[lane] = p;
    reinterpret_cast<float4*>(out + (size_t)(N + n) * NEXP)[lane] = m;
}

extern "C" void kernel_launch(void* const* d_in, const int* in_sizes, int n_in,
                              void* d_out, int out_size, void* d_ws, size_t ws_size,
                              hipStream_t stream) {
    const float* hidden    = (const float*)d_in[0];
    const int*   token_ids = (const int*)d_in[1];   // int64 in ref -> int32 here
    const float* weight    = (const float*)d_in[2];
    const int*   tid2eid   = (const int*)d_in[3];
    float* out = (float*)d_out;
    const int N = in_sizes[1];  // B*S tokens

    const int nblocks = (N + WPT - 1) / WPT;
    const size_t need = (size_t)NEXP * DIM * sizeof(unsigned short);  // 1 MiB
    if (ws_size >= need) {
        unsigned int* wh = (unsigned int*)d_ws;
        const int n4 = NEXP * DIM / 4;
        convert_weight_f16<<<(n4 + 255) / 256, 256, 0, stream>>>(weight, wh, n4);
        router_v5<true><<<nblocks, 512, 0, stream>>>(hidden, token_ids, wh, tid2eid, out, N);
    } else {
        router_v5<false><<<nblocks, 512, 0, stream>>>(hidden, token_ids, weight, tid2eid, out, N);
    }
}

// Round 12
// 39.058 us; speedup vs baseline: 2.1230x; 1.1771x over previous
//
#include <hip/hip_runtime.h>
#include <hip/hip_fp16.h>

// DeepseekV4HashRouter: B=4,S=4096,D=2048,E=256,K=8,V=128000
#define DIM    2048
#define NEXP   256
#define TOPK   8
#define RSCALE 2.5f
#define WPT    4          // waves (tokens) per 256-thread block
#define WSCALE 64.0f      // weight pre-scale into e4m3 normal range
#define INV_WSCALE 0.015625f

typedef float f2 __attribute__((ext_vector_type(2)));

// fp32 -> fp8 e4m3 (x64), 4 weights per u32, RNE in hardware.
__global__ __launch_bounds__(256) void convert_weight_fp8(
    const float* __restrict__ w, unsigned int* __restrict__ w8, int n4) {
    int i = blockIdx.x * blockDim.x + threadIdx.x;  // over float4s
    if (i < n4) {
        float4 f = reinterpret_cast<const float4*>(w)[i];
        int r = 0;
        r = __builtin_amdgcn_cvt_pk_fp8_f32(f.x * WSCALE, f.y * WSCALE, r, false);
        r = __builtin_amdgcn_cvt_pk_fp8_f32(f.z * WSCALE, f.w * WSCALE, r, true);
        w8[i] = (unsigned int)r;
    }
}

// One 64-lane wave per token; fp8 weight rows (2KB each -> 2 loads/expert),
// HW fp8->f32 unpack + f32 fma; SGPR expert bases; tournament reduce.
__global__ __launch_bounds__(256) void router_fp8(
    const float* __restrict__ hidden,   // [N, D] fp32
    const int* __restrict__ token_ids,  // [N] int32
    const uint4* __restrict__ w8,       // [E, D] fp8 (e4m3, x64)
    const int* __restrict__ tid2eid,    // [V, K] int32
    float* __restrict__ out,            // probs [N,E] then map [N,E]
    int N) {
    const int lane = threadIdx.x & 63;
    const int n = blockIdx.x * WPT + (threadIdx.x >> 6);
    if (n >= N) return;

    // Wave-uniform token id / expert ids -> SGPRs.
    const int tid = __builtin_amdgcn_readfirstlane(token_ids[n]);
    const int* er = tid2eid + (size_t)tid * TOPK;
    int eidx[TOPK];
#pragma unroll
    for (int k = 0; k < TOPK; ++k)
        eidx[k] = __builtin_amdgcn_readfirstlane(er[k]);

    // Expert row e: 2048 fp8 bytes = 128 uint4.
    const uint4* wb[TOPK];
#pragma unroll
    for (int k = 0; k < TOPK; ++k)
        wb[k] = w8 + (size_t)eidx[k] * (DIM / 16);

    const float4* h4 = reinterpret_cast<const float4*>(hidden + (size_t)n * DIM);

    float acc[TOPK] = {0.f, 0.f, 0.f, 0.f, 0.f, 0.f, 0.f, 0.f};

#pragma unroll
    for (int j = 0; j < 2; ++j) {
        // 8 independent 16B weight loads (16 fp8 each), distinct SGPR bases.
        uint4 wv[TOPK];
#pragma unroll
        for (int k = 0; k < TOPK; ++k) wv[k] = wb[k][j * 64 + lane];
        // This lane's 16 hidden floats for half j: floats [j*1024 + lane*16 ..).
        float4 hv[4];
#pragma unroll
        for (int i = 0; i < 4; ++i) hv[i] = h4[j * 256 + lane * 4 + i];

#pragma unroll
        for (int k = 0; k < TOPK; ++k) {
            const unsigned int* wu = reinterpret_cast<const unsigned int*>(&wv[k]);
            float s = acc[k];
#pragma unroll
            for (int c = 0; c < 4; ++c) {
                const int u = (int)wu[c];
                const f2 a = __builtin_amdgcn_cvt_pk_f32_fp8(u, false);
                const f2 b = __builtin_amdgcn_cvt_pk_f32_fp8(u, true);
                s = fmaf(hv[c].x, a.x, s);
                s = fmaf(hv[c].y, a.y, s);
                s = fmaf(hv[c].z, b.x, s);
                s = fmaf(hv[c].w, b.y, s);
            }
            acc[k] = s;
        }
    }

    // Tournament reduce: 8 values/lane -> 1 value/lane in 7 shfls + 3 butterfly.
    const int b0 = lane & 1, b1 = (lane >> 1) & 1, b2 = (lane >> 2) & 1;
    float v4[4];
#pragma unroll
    for (int k = 0; k < 4; ++k) {
        const float send = b0 ? acc[k] : acc[k + 4];
        const float recv = __shfl_xor(send, 1, 64);
        v4[k] = (b0 ? acc[k + 4] : acc[k]) + recv;
    }
    float v2[2];
#pragma unroll
    for (int j = 0; j < 2; ++j) {
        const float send = b1 ? v4[j] : v4[j + 2];
        const float recv = __shfl_xor(send, 2, 64);
        v2[j] = (b1 ? v4[j + 2] : v4[j]) + recv;
    }
    {
        const float send = b2 ? v2[0] : v2[1];
        const float recv = __shfl_xor(send, 4, 64);
        v2[0] = (b2 ? v2[1] : v2[0]) + recv;
    }
    float v = v2[0];
    v += __shfl_xor(v, 8, 64);
    v += __shfl_xor(v, 16, 64);
    v += __shfl_xor(v, 32, 64);
    v *= INV_WSCALE;  // undo e4m3 pre-scale
    // Lane l holds logit of expert slot e(l) = 4*b0 + 2*b1 + b2.

    const float sp = fmaxf(v, 0.0f) + log1pf(expf(-fabsf(v)));
    const float score = sqrtf(sp);

    // Slot k lives in lane bit-rev3(k).
    float sc[TOPK];
    float denom = 0.0f;
#pragma unroll
    for (int k = 0; k < TOPK; ++k) {
        const int src = ((k >> 2) & 1) | (k & 2) | ((k & 1) << 2);
        sc[k] = __shfl(score, src, 64);
        denom += sc[k];
    }
    const float inv = RSCALE / fmaxf(denom, 1e-12f);

    // Dense vectorized write: lane l owns experts 4l..4l+3.
    float4 p, m;
    float* pp = reinterpret_cast<float*>(&p);
    float* mm = reinterpret_cast<float*>(&m);
#pragma unroll
    for (int c = 0; c < 4; ++c) {
        const int e = lane * 4 + c;
        float pv = 0.0f, mv = 0.0f;
#pragma unroll
        for (int k = 0; k < TOPK; ++k) {
            if (eidx[k] == e) { pv = sc[k] * inv; mv = 1.0f; }
        }
        pp[c] = pv; mm[c] = mv;
    }
    reinterpret_cast<float4*>(out + (size_t)n * NEXP)[lane] = p;
    reinterpret_cast<float4*>(out + (size_t)(N + n) * NEXP)[lane] = m;
}

// Fallback (no workspace): fp32 gather, one wave per token.
__global__ __launch_bounds__(256) void router_fp32(
    const float* __restrict__ hidden, const int* __restrict__ token_ids,
    const float* __restrict__ weight, const int* __restrict__ tid2eid,
    float* __restrict__ out, int N) {
    const int lane = threadIdx.x & 63;
    const int n = blockIdx.x * 4 + (threadIdx.x >> 6);
    if (n >= N) return;
    const int tid = token_ids[n];
    const int* er = tid2eid + (size_t)tid * TOPK;
    int eidx[TOPK];
#pragma unroll
    for (int k = 0; k < TOPK; ++k) eidx[k] = er[k];
    const float4* h4 = reinterpret_cast<const float4*>(hidden + (size_t)n * DIM);
    float acc[TOPK] = {};
#pragma unroll
    for (int j = 0; j < 4; ++j) {
        const float4 a = h4[j * 128 + lane * 2];
        const float4 b = h4[j * 128 + lane * 2 + 1];
#pragma unroll
        for (int k = 0; k < TOPK; ++k) {
            const float4* wr = reinterpret_cast<const float4*>(weight + (size_t)eidx[k] * DIM);
            const float4 wa = wr[j * 128 + lane * 2];
            const float4 wb = wr[j * 128 + lane * 2 + 1];
            acc[k] += a.x * wa.x + a.y * wa.y + a.z * wa.z + a.w * wa.w
                    + b.x * wb.x + b.y * wb.y + b.z * wb.z + b.w * wb.w;
        }
    }
#pragma unroll
    for (int k = 0; k < TOPK; ++k) {
        float v = acc[k];
#pragma unroll
        for (int m = 1; m < 64; m <<= 1) v += __shfl_xor(v, m, 64);
        acc[k] = v;
    }
    float sval = 0.0f;
    if (lane < TOPK) {
        const float sp = fmaxf(acc[lane], 0.0f) + log1pf(expf(-fabsf(acc[lane])));
        sval = sqrtf(sp);
    }
    float sc[TOPK]; float denom = 0.0f;
#pragma unroll
    for (int k = 0; k < TOPK; ++k) { sc[k] = __shfl(sval, k, 64); denom += sc[k]; }
    const float inv = RSCALE / fmaxf(denom, 1e-12f);
    float4 p, mv;
    float* pp = reinterpret_cast<float*>(&p);
    float* mm = reinterpret_cast<float*>(&mv);
#pragma unroll
    for (int c = 0; c < 4; ++c) {
        const int e = lane * 4 + c;
        float pv = 0.0f, fv = 0.0f;
#pragma unroll
        for (int k = 0; k < TOPK; ++k)
            if (eidx[k] == e) { pv = sc[k] * inv; fv = 1.0f; }
        pp[c] = pv; mm[c] = fv;
    }
    reinterpret_cast<float4*>(out + (size_t)n * NEXP)[lane] = p;
    reinterpret_cast<float4*>(out + (size_t)(N + n) * NEXP)[lane] = mv;
}

extern "C" void kernel_launch(void* const* d_in, const int* in_sizes, int n_in,
                              void* d_out, int out_size, void* d_ws, size_t ws_size,
                              hipStream_t stream) {
    const float* hidden    = (const float*)d_in[0];
    const int*   token_ids = (const int*)d_in[1];   // int64 in ref -> int32 here
    const float* weight    = (const float*)d_in[2];
    const int*   tid2eid   = (const int*)d_in[3];
    float* out = (float*)d_out;
    const int N = in_sizes[1];  // B*S tokens

    const int nblocks = (N + WPT - 1) / WPT;
    const size_t need = (size_t)NEXP * DIM;  // 512 KiB of fp8
    if (ws_size >= need) {
        unsigned int* w8 = (unsigned int*)d_ws;
        const int n4 = NEXP * DIM / 4;
        convert_weight_fp8<<<(n4 + 255) / 256, 256, 0, stream>>>(weight, w8, n4);
        router_fp8<<<nblocks, 256, 0, stream>>>(hidden, token_ids,
                                                (const uint4*)w8, tid2eid, out, N);
    } else {
        router_fp32<<<nblocks, 256, 0, stream>>>(hidden, token_ids, weight,
                                                 tid2eid, out, N);
    }
}

// Round 13
// 38.313 us; speedup vs baseline: 2.1643x; 1.0194x over previous
//
#include <hip/hip_runtime.h>
#include <hip/hip_fp16.h>

// DeepseekV4HashRouter: B=4,S=4096,D=2048,E=256,K=8,V=128000
#define DIM    2048
#define NEXP   256
#define TOPK   8
#define RSCALE 2.5f
#define WPT    4          // waves (tokens) per 256-thread block
#define WSCALE 64.0f      // weight pre-scale into e4m3 normal range
#define INV_WSCALE 0.015625f

typedef float f2 __attribute__((ext_vector_type(2)));

// fp32 -> fp8 e4m3 (x64), PERMUTED so router's lane-contiguous uint4 load
// matches lane-contiguous hidden float4 loads:
//   w8p[e][u=j*64+lane].dword[c] = w[e][j*1024 + c*256 + lane*4 .. +4]
__global__ __launch_bounds__(256) void convert_weight_fp8p(
    const float* __restrict__ w, uint4* __restrict__ w8p) {
    const int t    = blockIdx.x * blockDim.x + threadIdx.x;  // 0 .. E*128-1
    const int e    = t >> 7;
    const int u    = t & 127;        // j*64 + lane
    const int j    = u >> 6;
    const int lane = u & 63;
    const float4* src = reinterpret_cast<const float4*>(w) + (size_t)e * 512 + j * 256 + lane;
    uint4 o;
    unsigned int* od = reinterpret_cast<unsigned int*>(&o);
#pragma unroll
    for (int c = 0; c < 4; ++c) {
        const float4 f = src[c * 64];
        int r = 0;
        r = __builtin_amdgcn_cvt_pk_fp8_f32(f.x * WSCALE, f.y * WSCALE, r, false);
        r = __builtin_amdgcn_cvt_pk_fp8_f32(f.z * WSCALE, f.w * WSCALE, r, true);
        od[c] = (unsigned int)r;
    }
    w8p[(size_t)e * 128 + u] = o;
}

// One 64-lane wave per token; permuted fp8 weight rows; all vmem accesses
// lane-contiguous (hidden 1KB/instr, weight 1KB/instr); SGPR expert bases.
__global__ __launch_bounds__(256) void router_fp8(
    const float* __restrict__ hidden,   // [N, D] fp32
    const int* __restrict__ token_ids,  // [N] int32
    const uint4* __restrict__ w8,       // [E, D] fp8 permuted
    const int* __restrict__ tid2eid,    // [V, K] int32
    float* __restrict__ out,            // probs [N,E] then map [N,E]
    int N) {
    const int lane = threadIdx.x & 63;
    const int n = blockIdx.x * WPT + (threadIdx.x >> 6);
    if (n >= N) return;

    // Wave-uniform token id / expert ids -> SGPRs.
    const int tid = __builtin_amdgcn_readfirstlane(token_ids[n]);
    const int* er = tid2eid + (size_t)tid * TOPK;
    int eidx[TOPK];
#pragma unroll
    for (int k = 0; k < TOPK; ++k)
        eidx[k] = __builtin_amdgcn_readfirstlane(er[k]);

    const uint4* wb[TOPK];
#pragma unroll
    for (int k = 0; k < TOPK; ++k)
        wb[k] = w8 + (size_t)eidx[k] * (DIM / 16);

    const float4* h4 = reinterpret_cast<const float4*>(hidden + (size_t)n * DIM);

    float acc[TOPK] = {0.f, 0.f, 0.f, 0.f, 0.f, 0.f, 0.f, 0.f};

#pragma unroll
    for (int j = 0; j < 2; ++j) {
        // 8 independent 16B weight loads (distinct SGPR bases, lane-contiguous).
        uint4 wv[TOPK];
#pragma unroll
        for (int k = 0; k < TOPK; ++k) wv[k] = wb[k][j * 64 + lane];
        // Hidden: 4 lane-contiguous float4 loads; lane's elems
        // {j*1024 + i*256 + lane*4 .. +4} match weight dword i (permuted).
        float4 hv[4];
#pragma unroll
        for (int i = 0; i < 4; ++i) hv[i] = h4[j * 256 + i * 64 + lane];

#pragma unroll
        for (int k = 0; k < TOPK; ++k) {
            const unsigned int* wu = reinterpret_cast<const unsigned int*>(&wv[k]);
            float s = acc[k];
#pragma unroll
            for (int c = 0; c < 4; ++c) {
                const int u = (int)wu[c];
                const f2 a = __builtin_amdgcn_cvt_pk_f32_fp8(u, false);
                const f2 b = __builtin_amdgcn_cvt_pk_f32_fp8(u, true);
                s = fmaf(hv[c].x, a.x, s);
                s = fmaf(hv[c].y, a.y, s);
                s = fmaf(hv[c].z, b.x, s);
                s = fmaf(hv[c].w, b.y, s);
            }
            acc[k] = s;
        }
    }

    // Tournament reduce: 8 values/lane -> 1 value/lane in 7 shfls + 3 butterfly.
    const int b0 = lane & 1, b1 = (lane >> 1) & 1, b2 = (lane >> 2) & 1;
    float v4[4];
#pragma unroll
    for (int k = 0; k < 4; ++k) {
        const float send = b0 ? acc[k] : acc[k + 4];
        const float recv = __shfl_xor(send, 1, 64);
        v4[k] = (b0 ? acc[k + 4] : acc[k]) + recv;
    }
    float v2[2];
#pragma unroll
    for (int j = 0; j < 2; ++j) {
        const float send = b1 ? v4[j] : v4[j + 2];
        const float recv = __shfl_xor(send, 2, 64);
        v2[j] = (b1 ? v4[j + 2] : v4[j]) + recv;
    }
    {
        const float send = b2 ? v2[0] : v2[1];
        const float recv = __shfl_xor(send, 4, 64);
        v2[0] = (b2 ? v2[1] : v2[0]) + recv;
    }
    float v = v2[0];
    v += __shfl_xor(v, 8, 64);
    v += __shfl_xor(v, 16, 64);
    v += __shfl_xor(v, 32, 64);
    v *= INV_WSCALE;  // undo e4m3 pre-scale
    // Lane l holds logit of expert slot e(l) = 4*b0 + 2*b1 + b2.

    const float sp = fmaxf(v, 0.0f) + log1pf(expf(-fabsf(v)));
    const float score = sqrtf(sp);

    // Slot k lives in lane bit-rev3(k).
    float sc[TOPK];
    float denom = 0.0f;
#pragma unroll
    for (int k = 0; k < TOPK; ++k) {
        const int src = ((k >> 2) & 1) | (k & 2) | ((k & 1) << 2);
        sc[k] = __shfl(score, src, 64);
        denom += sc[k];
    }
    const float inv = RSCALE / fmaxf(denom, 1e-12f);

    // Dense vectorized write: lane l owns experts 4l..4l+3.
    float4 p, m;
    float* pp = reinterpret_cast<float*>(&p);
    float* mm = reinterpret_cast<float*>(&m);
#pragma unroll
    for (int c = 0; c < 4; ++c) {
        const int e = lane * 4 + c;
        float pv = 0.0f, mv = 0.0f;
#pragma unroll
        for (int k = 0; k < TOPK; ++k) {
            if (eidx[k] == e) { pv = sc[k] * inv; mv = 1.0f; }
        }
        pp[c] = pv; mm[c] = mv;
    }
    reinterpret_cast<float4*>(out + (size_t)n * NEXP)[lane] = p;
    reinterpret_cast<float4*>(out + (size_t)(N + n) * NEXP)[lane] = m;
}

// Fallback (no workspace): fp32 gather, one wave per token.
__global__ __launch_bounds__(256) void router_fp32(
    const float* __restrict__ hidden, const int* __restrict__ token_ids,
    const float* __restrict__ weight, const int* __restrict__ tid2eid,
    float* __restrict__ out, int N) {
    const int lane = threadIdx.x & 63;
    const int n = blockIdx.x * 4 + (threadIdx.x >> 6);
    if (n >= N) return;
    const int tid = token_ids[n];
    const int* er = tid2eid + (size_t)tid * TOPK;
    int eidx[TOPK];
#pragma unroll
    for (int k = 0; k < TOPK; ++k) eidx[k] = er[k];
    const float4* h4 = reinterpret_cast<const float4*>(hidden + (size_t)n * DIM);
    float acc[TOPK] = {};
#pragma unroll
    for (int j = 0; j < 4; ++j) {
        const float4 a = h4[j * 128 + lane * 2];
        const float4 b = h4[j * 128 + lane * 2 + 1];
#pragma unroll
        for (int k = 0; k < TOPK; ++k) {
            const float4* wr = reinterpret_cast<const float4*>(weight + (size_t)eidx[k] * DIM);
            const float4 wa = wr[j * 128 + lane * 2];
            const float4 wb = wr[j * 128 + lane * 2 + 1];
            acc[k] += a.x * wa.x + a.y * wa.y + a.z * wa.z + a.w * wa.w
                    + b.x * wb.x + b.y * wb.y + b.z * wb.z + b.w * wb.w;
        }
    }
#pragma unroll
    for (int k = 0; k < TOPK; ++k) {
        float v = acc[k];
#pragma unroll
        for (int m = 1; m < 64; m <<= 1) v += __shfl_xor(v, m, 64);
        acc[k] = v;
    }
    float sval = 0.0f;
    if (lane < TOPK) {
        const float sp = fmaxf(acc[lane], 0.0f) + log1pf(expf(-fabsf(acc[lane])));
        sval = sqrtf(sp);
    }
    float sc[TOPK]; float denom = 0.0f;
#pragma unroll
    for (int k = 0; k < TOPK; ++k) { sc[k] = __shfl(sval, k, 64); denom += sc[k]; }
    const float inv = RSCALE / fmaxf(denom, 1e-12f);
    float4 p, mv;
    float* pp = reinterpret_cast<float*>(&p);
    float* mm = reinterpret_cast<float*>(&mv);
#pragma unroll
    for (int c = 0; c < 4; ++c) {
        const int e = lane * 4 + c;
        float pv = 0.0f, fv = 0.0f;
#pragma unroll
        for (int k = 0; k < TOPK; ++k)
            if (eidx[k] == e) { pv = sc[k] * inv; fv = 1.0f; }
        pp[c] = pv; mm[c] = fv;
    }
    reinterpret_cast<float4*>(out + (size_t)n * NEXP)[lane] = p;
    reinterpret_cast<float4*>(out + (size_t)(N + n) * NEXP)[lane] = mv;
}

extern "C" void kernel_launch(void* const* d_in, const int* in_sizes, int n_in,
                              void* d_out, int out_size, void* d_ws, size_t ws_size,
                              hipStream_t stream) {
    const float* hidden    = (const float*)d_in[0];
    const int*   token_ids = (const int*)d_in[1];   // int64 in ref -> int32 here
    const float* weight    = (const float*)d_in[2];
    const int*   tid2eid   = (const int*)d_in[3];
    float* out = (float*)d_out;
    const int N = in_sizes[1];  // B*S tokens

    const int nblocks = (N + WPT - 1) / WPT;
    const size_t need = (size_t)NEXP * DIM;  // 512 KiB of fp8
    if (ws_size >= need) {
        uint4* w8 = (uint4*)d_ws;
        const int nt = NEXP * 128;  // one thread per uint4
        convert_weight_fp8p<<<nt / 256, 256, 0, stream>>>(weight, w8);
        router_fp8<<<nblocks, 256, 0, stream>>>(hidden, token_ids,
                                                (const uint4*)w8, tid2eid, out, N);
    } else {
        router_fp32<<<nblocks, 256, 0, stream>>>(hidden, token_ids, weight,
                                                 tid2eid, out, N);
    }
}